// Round 4
// baseline (191.180 us; speedup 1.0000x reference)
//
#include <hip/hip_runtime.h>
#include <hip/hip_bf16.h>

// SparseDropout, fused single-launch, 32B-per-lane version:
//   units [0, n_idx8):       out0 = (float)indices  (int8x -> float8x)
//   units [n_idx8, n_tot8):  out1 = mask ? values*2 : 0
// 32B/lane = 2x global_load_dwordx4 in flight per thread per iteration,
// 2KB contiguous per wave. Nontemporal: pure streaming, zero reuse.

typedef int   i32x8 __attribute__((ext_vector_type(8)));
typedef float f32x8 __attribute__((ext_vector_type(8)));

__global__ __launch_bounds__(256) void sd_fused(const int* __restrict__ idx,
                                                const float* __restrict__ vals,
                                                const int* __restrict__ mask,
                                                float* __restrict__ out_idx,
                                                float* __restrict__ out_val,
                                                long long n_idx8,
                                                long long n_tot8) {
    long long i = (long long)blockIdx.x * blockDim.x + threadIdx.x;
    const long long stride = (long long)gridDim.x * blockDim.x;
    const float scale = 2.0f;  // 1 / KPROB, KPROB = 0.5

    for (; i < n_tot8; i += stride) {
        if (i < n_idx8) {
            i32x8 v = __builtin_nontemporal_load((const i32x8*)idx + i);
            f32x8 o;
            #pragma unroll
            for (int k = 0; k < 8; ++k) o[k] = (float)v[k];
            __builtin_nontemporal_store(o, (f32x8*)out_idx + i);
        } else {
            long long j = i - n_idx8;
            f32x8 v = __builtin_nontemporal_load((const f32x8*)vals + j);
            i32x8 m = __builtin_nontemporal_load((const i32x8*)mask + j);
            f32x8 o;
            #pragma unroll
            for (int k = 0; k < 8; ++k) o[k] = m[k] ? v[k] * scale : 0.0f;
            __builtin_nontemporal_store(o, (f32x8*)out_val + j);
        }
    }
}

extern "C" void kernel_launch(void* const* d_in, const int* in_sizes, int n_in,
                              void* d_out, int out_size, void* d_ws, size_t ws_size,
                              hipStream_t stream) {
    const int* indices = (const int*)d_in[0];    // (2, NNZ) flattened int32
    const float* values = (const float*)d_in[1]; // (NNZ,) f32
    const int* mask = (const int*)d_in[2];       // (NNZ,) bool -> int32

    const long long n_idx = in_sizes[0];  // 64,000,000
    const long long n_val = in_sizes[1];  // 32,000,000

    float* out_idx = (float*)d_out;
    float* out_val = (float*)d_out + n_idx;

    const long long n_idx8 = n_idx / 8;            // 8M   (64M % 8 == 0)
    const long long n_tot8 = n_idx8 + n_val / 8;   // 12M  (32M % 8 == 0)

    const int block = 256;
    int grid = (int)((n_tot8 + block - 1) / block);
    if (grid > 2048) grid = 2048;

    sd_fused<<<grid, block, 0, stream>>>(indices, values, mask,
                                         out_idx, out_val, n_idx8, n_tot8);
}

// Round 5
// 168.183 us; speedup vs baseline: 1.1367x; 1.1367x over previous
//
#include <hip/hip_runtime.h>
#include <hip/hip_bf16.h>

// SparseDropout, fused single-launch, dense 16B/lane + unroll-by-2:
//   units [0, n_idx4):       out0 = (float)indices  (int4 -> float4)
//   units [n_idx4, n_tot4):  out1 = mask ? values*2 : 0
// R4 lesson: 32B/lane vectors regress (strided dwordx4 halves per-instruction
// coalescing density). Keep 16B/lane dense; get MLP via 2 independent
// load->store chains per loop iteration instead.

typedef int   i32x4 __attribute__((ext_vector_type(4)));
typedef float f32x4 __attribute__((ext_vector_type(4)));

__device__ __forceinline__ void process_unit(long long i,
                                             const int* __restrict__ idx,
                                             const float* __restrict__ vals,
                                             const int* __restrict__ mask,
                                             float* __restrict__ out_idx,
                                             float* __restrict__ out_val,
                                             long long n_idx4) {
    const float scale = 2.0f;  // 1 / KPROB
    if (i < n_idx4) {
        i32x4 v = __builtin_nontemporal_load((const i32x4*)idx + i);
        f32x4 o;
        o.x = (float)v.x;
        o.y = (float)v.y;
        o.z = (float)v.z;
        o.w = (float)v.w;
        __builtin_nontemporal_store(o, (f32x4*)out_idx + i);
    } else {
        long long j = i - n_idx4;
        f32x4 v = __builtin_nontemporal_load((const f32x4*)vals + j);
        i32x4 m = __builtin_nontemporal_load((const i32x4*)mask + j);
        f32x4 o;
        o.x = m.x ? v.x * scale : 0.0f;
        o.y = m.y ? v.y * scale : 0.0f;
        o.z = m.z ? v.z * scale : 0.0f;
        o.w = m.w ? v.w * scale : 0.0f;
        __builtin_nontemporal_store(o, (f32x4*)out_val + j);
    }
}

__global__ __launch_bounds__(256) void sd_fused(const int* __restrict__ idx,
                                                const float* __restrict__ vals,
                                                const int* __restrict__ mask,
                                                float* __restrict__ out_idx,
                                                float* __restrict__ out_val,
                                                long long n_idx4,
                                                long long n_tot4) {
    const long long stride = (long long)gridDim.x * blockDim.x;
    long long i = (long long)blockIdx.x * blockDim.x + threadIdx.x;

    // Unrolled by 2: two independent load->store chains per iteration.
    for (; i + stride < n_tot4; i += 2 * stride) {
        process_unit(i, idx, vals, mask, out_idx, out_val, n_idx4);
        process_unit(i + stride, idx, vals, mask, out_idx, out_val, n_idx4);
    }
    if (i < n_tot4) {
        process_unit(i, idx, vals, mask, out_idx, out_val, n_idx4);
    }
}

extern "C" void kernel_launch(void* const* d_in, const int* in_sizes, int n_in,
                              void* d_out, int out_size, void* d_ws, size_t ws_size,
                              hipStream_t stream) {
    const int* indices = (const int*)d_in[0];    // (2, NNZ) flattened int32
    const float* values = (const float*)d_in[1]; // (NNZ,) f32
    const int* mask = (const int*)d_in[2];       // (NNZ,) bool -> int32

    const long long n_idx = in_sizes[0];  // 64,000,000
    const long long n_val = in_sizes[1];  // 32,000,000

    float* out_idx = (float*)d_out;
    float* out_val = (float*)d_out + n_idx;

    const long long n_idx4 = n_idx / 4;            // 16M
    const long long n_tot4 = n_idx4 + n_val / 4;   // 24M

    const int block = 256;
    int grid = (int)((n_tot4 + block - 1) / block);
    if (grid > 2048) grid = 2048;

    sd_fused<<<grid, block, 0, stream>>>(indices, values, mask,
                                         out_idx, out_val, n_idx4, n_tot4);
}

// Round 6
// 141.848 us; speedup vs baseline: 1.3478x; 1.1857x over previous
//
#include <hip/hip_runtime.h>
#include <hip/hip_bf16.h>

// SparseDropout, fused, FLAT launch (one 16B unit per thread, no loop):
//   units [0, n_idx4):       out0 = (float)indices  (int4 -> float4)
//   units [n_idx4, n_tot4):  out1 = mask ? values*2 : 0
// Rationale: grid-stride @2048 blocks = 8192 concurrent 8MB-apart address
// streams -> DRAM row thrash. Flat launch makes in-flight blocks cover a
// moving contiguous window (dispatch-order locality), like the 6.9 TB/s
// harness fills. 24M units / 256 = 93750 blocks exactly, no tail.

typedef int   i32x4 __attribute__((ext_vector_type(4)));
typedef float f32x4 __attribute__((ext_vector_type(4)));

__global__ __launch_bounds__(256) void sd_fused_flat(const int* __restrict__ idx,
                                                     const float* __restrict__ vals,
                                                     const int* __restrict__ mask,
                                                     float* __restrict__ out_idx,
                                                     float* __restrict__ out_val,
                                                     long long n_idx4) {
    const long long i = (long long)blockIdx.x * blockDim.x + threadIdx.x;
    const float scale = 2.0f;  // 1 / KPROB, KPROB = 0.5

    if (i < n_idx4) {
        i32x4 v = __builtin_nontemporal_load((const i32x4*)idx + i);
        f32x4 o;
        o.x = (float)v.x;
        o.y = (float)v.y;
        o.z = (float)v.z;
        o.w = (float)v.w;
        __builtin_nontemporal_store(o, (f32x4*)out_idx + i);
    } else {
        long long j = i - n_idx4;
        f32x4 v = __builtin_nontemporal_load((const f32x4*)vals + j);
        i32x4 m = __builtin_nontemporal_load((const i32x4*)mask + j);
        f32x4 o;
        o.x = m.x ? v.x * scale : 0.0f;
        o.y = m.y ? v.y * scale : 0.0f;
        o.z = m.z ? v.z * scale : 0.0f;
        o.w = m.w ? v.w * scale : 0.0f;
        __builtin_nontemporal_store(o, (f32x4*)out_val + j);
    }
}

extern "C" void kernel_launch(void* const* d_in, const int* in_sizes, int n_in,
                              void* d_out, int out_size, void* d_ws, size_t ws_size,
                              hipStream_t stream) {
    const int* indices = (const int*)d_in[0];    // (2, NNZ) flattened int32
    const float* values = (const float*)d_in[1]; // (NNZ,) f32
    const int* mask = (const int*)d_in[2];       // (NNZ,) bool -> int32

    const long long n_idx = in_sizes[0];  // 64,000,000
    const long long n_val = in_sizes[1];  // 32,000,000

    float* out_idx = (float*)d_out;
    float* out_val = (float*)d_out + n_idx;

    const long long n_idx4 = n_idx / 4;            // 16M
    const long long n_tot4 = n_idx4 + n_val / 4;   // 24M

    const int block = 256;
    // 24M % 256 == 0 -> exact grid, but keep the guard arithmetic general.
    long long grid_ll = (n_tot4 + block - 1) / block;  // 93750
    int grid = (int)grid_ll;

    sd_fused_flat<<<grid, block, 0, stream>>>(indices, values, mask,
                                              out_idx, out_val, n_idx4);
}